// Round 6
// baseline (310.568 us; speedup 1.0000x reference)
//
#include <hip/hip_runtime.h>
#include <math.h>

// GroupedQueryAttention: B=4,S=128,D=4096,H=32,KV=8,HD=128,REP=4
// Round 12: fix r11's LDS bank conflicts (3.1M, the regression vs r0).
//  - BK=32 staging now uses a both-sides XOR chunk swizzle: source chunk
//    c^((r>>1)&3) -> linear LDS (DMA-compatible), fragment read at
//    quad^((row>>1)&3). 16-lane read group = 8 bank-starts x 2 lanes = free.
//  - prep: pad dropped (tile [64][128] = 32KB -> 5 blocks/CU; swizzle alone
//    already gives 0 conflicts, r10-measured) + 2 k-tiles per block with
//    tile-1 loads issued before tile-0's store phase (latency hiding).
//  - everything else: r11 structure (z=4 split-K, counted vmcnt(4) triple
//    buffer, packed wo-T, reduce/rope, attn, o_reduce).

#define B_   4
#define S_   128
#define D_   4096
#define H_   32
#define KV_  8
#define HD_  128
#define M_   (B_ * S_)        // 512 rows
#define NQKV 6144
#define SCALE_ 0.088388347648318447f  // 1/sqrt(128)

typedef _Float16 half_t;
typedef half_t f16x8 __attribute__((ext_vector_type(8)));
typedef float  f32x4 __attribute__((ext_vector_type(4)));

__device__ inline void load_lds16(const void* g, void* l) {
    __builtin_amdgcn_global_load_lds((const __attribute__((address_space(1))) void*)g,
                                     (__attribute__((address_space(3))) void*)l,
                                     16, 0, 0);
}

// ---------------------------------------------------------------------------
// Store phase of a transpose tile: LDS [64][128] fp32 (chunk-XOR-swizzled)
// -> Wt slab rows ndst0..+128 x 64 halfs (16KB lane-contiguous store).
__device__ __forceinline__ void transpose_store(const float (*tile)[128], int t,
                                                size_t tb, half_t* __restrict__ Wt) {
    const int kh = (t >> 2) & 1, cc = t & 3, dd = t >> 3;
    const int rbase = kh * 32 + cc * 8;
    const int h3 = 4 * kh + cc;             // = (r>>3)&7 for rows rbase..+7
#pragma unroll
    for (int u = 0; u < 4; ++u) {
        int n = u * 32 + dd;
        int pc = ((n >> 2) ^ h3) * 4 + (n & 3);
        __align__(16) half_t hs[8];
#pragma unroll
        for (int i = 0; i < 8; ++i)
            hs[i] = (half_t)tile[rbase + i][pc];
        *(uint4*)&Wt[tb + (size_t)u * 2048 + t * 8] = *(uint4*)hs;
    }
}

// One 128n x 64k tile (used for wo-T inside the gemm launch).
__device__ void transpose_tile(const float* __restrict__ src, int Nsrc, int nsrc0,
                               int ndst0, int k0, int Ntot,
                               half_t* __restrict__ Wt, void* ldsraw) {
    float (*tile)[128] = (float(*)[128])ldsraw;   // [64k][128n], 32KB
    const int t = threadIdx.x;
#pragma unroll
    for (int p = 0; p < 8; ++p) {
        int idx = t + p * 256;
        int r = idx >> 5, c4 = idx & 31;
        *(float4*)&tile[r][(c4 ^ ((r >> 3) & 7)) * 4] =
            *(const float4*)&src[(size_t)(k0 + r) * Nsrc + nsrc0 + c4 * 4];
    }
    __syncthreads();
    transpose_store(tile, t, ((size_t)(k0 >> 6) * Ntot + ndst0) * 64, Wt);
}

// Two consecutive k-tiles, software-pipelined: tile1's global loads are
// issued before tile0's store phase (latency hidden under LDS reads+stores).
__device__ void transpose_tile2(const float* __restrict__ src, int Nsrc, int nsrc0,
                                int ndst0, int k0, int Ntot,
                                half_t* __restrict__ Wt, void* ldsraw) {
    float (*tile)[128] = (float(*)[128])ldsraw;
    const int t = threadIdx.x;
    int rr[8], cs[8];
#pragma unroll
    for (int p = 0; p < 8; ++p) {
        int idx = t + p * 256;
        rr[p] = idx >> 5; cs[p] = idx & 31;
    }
#pragma unroll
    for (int p = 0; p < 8; ++p)
        *(float4*)&tile[rr[p]][(cs[p] ^ ((rr[p] >> 3) & 7)) * 4] =
            *(const float4*)&src[(size_t)(k0 + rr[p]) * Nsrc + nsrc0 + cs[p] * 4];
    __syncthreads();
    float4 v1[8];
#pragma unroll
    for (int p = 0; p < 8; ++p)        // tile1 loads: in flight during store0
        v1[p] = *(const float4*)&src[(size_t)(k0 + 64 + rr[p]) * Nsrc + nsrc0 + cs[p] * 4];
    transpose_store(tile, t, ((size_t)(k0 >> 6) * Ntot + ndst0) * 64, Wt);
    __syncthreads();
#pragma unroll
    for (int p = 0; p < 8; ++p)
        *(float4*)&tile[rr[p]][(cs[p] ^ ((rr[p] >> 3) & 7)) * 4] = v1[p];
    __syncthreads();
    transpose_store(tile, t, ((size_t)((k0 + 64) >> 6) * Ntot + ndst0) * 64, Wt);
}

// ---------------------------------------------------------------------------
// Packed prep: QKV weight transpose (1536 double-tile blocks) + x->fp16 (512).
__global__ __launch_bounds__(256)
void prep_qkv(const float* __restrict__ wq, const float* __restrict__ wk,
              const float* __restrict__ wv, const float* __restrict__ x,
              half_t* __restrict__ Wt, half_t* __restrict__ x16) {
    __shared__ __align__(16) float lds[64][128];   // 32KB -> 5 blocks/CU
    const int bx = blockIdx.x;
    if (bx < 1536) {
        int nt = bx % 48, kt = bx / 48;     // kt 0..31 -> k0 = kt*128
        const float* src; int Nsrc, ns0, nd0;
        if (nt < 32)      { src = wq; Nsrc = 4096; ns0 = nt * 128;        nd0 = nt * 128; }
        else if (nt < 40) { src = wk; Nsrc = 1024; ns0 = (nt - 32) * 128; nd0 = 4096 + (nt - 32) * 128; }
        else              { src = wv; Nsrc = 1024; ns0 = (nt - 40) * 128; nd0 = 5120 + (nt - 40) * 128; }
        transpose_tile2(src, Nsrc, ns0, nd0, kt * 128, NQKV, Wt, lds);
    } else {
        int i0 = (bx - 1536) * 1024 + threadIdx.x;
#pragma unroll
        for (int j = 0; j < 4; ++j) {
            int i = i0 + j * 256;
            float4 f = ((const float4*)x)[i];
            __align__(8) half_t h4[4] = {(half_t)f.x, (half_t)f.y, (half_t)f.z, (half_t)f.w};
            ((uint2*)x16)[i] = *(uint2*)h4;
        }
    }
}

// ---------------------------------------------------------------------------
// 128x128 gemm core, BK=32, 256 threads (4 waves, each 64x64, acc[4][4]).
// 3 LDS buffers (A 8KB + B 8KB each = 48KB), depth-2 DMA prefetch, counted
// vmcnt(4) + raw s_barrier. Chunk-XOR swizzle (c ^ ((r>>1)&3)) on BOTH the
// global source (LDS dest stays lane-linear for DMA) and the fragment read:
// 16-lane read group = 8 bank-starts x 2 lanes = conflict-free.
__device__ __forceinline__ void stage_bk32(const half_t* __restrict__ A,
                                           const half_t* __restrict__ Bbase,
                                           int N, int m0, int n0, int kc,
                                           half_t* AsD, half_t* BsD, int tid) {
    const int lane = tid & 63, tB = tid & 192;
    const half_t* Bslab = Bbase + ((size_t)(kc >> 6) * N + n0) * 64 + ((kc >> 5) & 1) * 32;
#pragma unroll
    for (int p = 0; p < 2; ++p) {
        int tb = p * 256 + tB;              // wave-uniform LDS base
        int task = tb + lane;
        int r = task >> 2;
        int c = (task & 3) ^ ((r >> 1) & 3);   // pre-swizzled source chunk
        load_lds16(&A[(size_t)(m0 + r) * 4096 + kc + c * 8], AsD + tb * 8);
        load_lds16(&Bslab[(size_t)r * 64 + c * 8],           BsD + tb * 8);
    }
}

__device__ __forceinline__ void compute_bk32(const half_t* AsD, const half_t* BsD,
                                             int tid, f32x4 (&acc)[4][4]) {
    const int lane = tid & 63;
    const int quad = lane >> 4, l16 = lane & 15;
    const int w = tid >> 6;
    const int wm = (w & 1) * 64, wn = (w >> 1) * 64;
    half_t (*As)[32] = (half_t(*)[32])AsD;
    half_t (*Bs)[32] = (half_t(*)[32])BsD;
    f16x8 af[4], bf[4];
#pragma unroll
    for (int i = 0; i < 4; ++i) {
        int ra = wm + i * 16 + l16;
        af[i] = *(const f16x8*)&As[ra][(quad ^ ((ra >> 1) & 3)) * 8];
    }
#pragma unroll
    for (int j = 0; j < 4; ++j) {
        int rb = wn + j * 16 + l16;
        bf[j] = *(const f16x8*)&Bs[rb][(quad ^ ((rb >> 1) & 3)) * 8];
    }
#pragma unroll
    for (int i = 0; i < 4; ++i)
#pragma unroll
        for (int j = 0; j < 4; ++j)
            acc[i][j] = __builtin_amdgcn_mfma_f32_16x16x32_f16(af[i], bf[j], acc[i][j], 0, 0, 0);
}

__device__ __forceinline__ void fence4() {
    asm volatile("s_waitcnt vmcnt(4)" ::: "memory");
    __builtin_amdgcn_s_barrier();
    __builtin_amdgcn_sched_barrier(0);
}
__device__ __forceinline__ void fence0() {
    asm volatile("s_waitcnt vmcnt(0)" ::: "memory");
    __builtin_amdgcn_s_barrier();
    __builtin_amdgcn_sched_barrier(0);
}

__device__ __forceinline__ void gemm128_bk32(const half_t* __restrict__ A,
                                             const half_t* __restrict__ Bbase,
                                             int N, int m0, int n0, int kbase,
                                             int ksteps, char* lds,
                                             f32x4 (&acc)[4][4]) {
    const int tid = threadIdx.x;
    half_t* As0 = (half_t*)lds;              // [3][128][32] halfs, 8KB each
    half_t* Bs0 = (half_t*)(lds + 24576);    // [3][128][32]
    stage_bk32(A, Bbase, N, m0, n0, kbase,      As0,        Bs0,        tid);
    stage_bk32(A, Bbase, N, m0, n0, kbase + 32, As0 + 4096, Bs0 + 4096, tid);
    fence4();                                // tile0 landed; tile1 in flight
    int cur = 0, pf = 2;
    for (int it = 0; it < ksteps - 2; ++it) {
        stage_bk32(A, Bbase, N, m0, n0, kbase + (it + 2) * 32,
                   As0 + pf * 4096, Bs0 + pf * 4096, tid);
        compute_bk32(As0 + cur * 4096, Bs0 + cur * 4096, tid, acc);
        fence4();                            // tile it+1 landed; it+2 in flight
        cur = (cur == 2) ? 0 : cur + 1;
        pf  = (pf  == 2) ? 0 : pf  + 1;
    }
    compute_bk32(As0 + cur * 4096, Bs0 + cur * 4096, tid, acc);
    fence0();                                // last tile landed
    cur = (cur == 2) ? 0 : cur + 1;
    compute_bk32(As0 + cur * 4096, Bs0 + cur * 4096, tid, acc);
}

// ---------------------------------------------------------------------------
// Packed: QKV gemm (192*z blocks, z=4 split-K) + wo transpose (2048 blocks).
__global__ __launch_bounds__(256, 3)
void gemm_qkv_pack(const half_t* __restrict__ x16, const half_t* __restrict__ Wt,
                   float* __restrict__ Part, int kslice, int gemmBlocks,
                   const float* __restrict__ wo, half_t* __restrict__ WtO) {
    __shared__ __align__(16) char lds[49152];
    const int bx = blockIdx.x;
    if (bx < gemmBlocks) {
        const int nb = bx % 48, mb = (bx / 48) & 3, zi = bx / 192;
        const int m0 = mb * 128, n0 = nb * 128;
        f32x4 acc[4][4] = {};
        gemm128_bk32(x16, Wt, NQKV, m0, n0, zi * kslice, kslice / 32, lds, acc);
        const int tid = threadIdx.x;
        const int lane = tid & 63;
        const int quad = lane >> 4, l16 = lane & 15;
        const int w = tid >> 6;
        const int wm = (w & 1) * 64, wn = (w >> 1) * 64;
        float* Cp = Part + (size_t)zi * ((size_t)M_ * NQKV);
#pragma unroll
        for (int i = 0; i < 4; ++i)
#pragma unroll
            for (int j = 0; j < 4; ++j) {
                int col = n0 + wn + j * 16 + l16;
                int rowb = m0 + wm + i * 16 + quad * 4;
#pragma unroll
                for (int rg = 0; rg < 4; ++rg)
                    Cp[(size_t)(rowb + rg) * NQKV + col] = acc[i][j][rg];
            }
    } else {
        int t = bx - gemmBlocks;
        transpose_tile(wo, 4096, (t & 31) * 128, (t & 31) * 128, (t >> 5) * 64,
                       4096, WtO, lds);
    }
}

// ---------------------------------------------------------------------------
// sum_z Part + bias + RoPE -> fp16 q16 [M][4096], k16 [M][1024],
// vt16 [B][KV][HD][S]. Grid (12, 512).
__global__ void qkv_reduce_rope(const float* __restrict__ Part, int nz,
                                const float* __restrict__ bq, const float* __restrict__ bk,
                                const float* __restrict__ bv,
                                const float* __restrict__ fc, const float* __restrict__ fs,
                                half_t* __restrict__ q16, half_t* __restrict__ k16,
                                half_t* __restrict__ vt16) {
    const int row = blockIdx.y;          // b*128 + i
    const int col = (blockIdx.x * 256 + threadIdx.x) * 2;
    const size_t off = (size_t)row * NQKV + col;
    float2 s = *(const float2*)&Part[off];
    for (int z = 1; z < nz; ++z) {
        float2 p = *(const float2*)&Part[(size_t)z * ((size_t)M_ * NQKV) + off];
        s.x += p.x; s.y += p.y;
    }
    float2 bi;
    if (col < 4096)      bi = *(const float2*)&bq[col];
    else if (col < 5120) bi = *(const float2*)&bk[col - 4096];
    else                 bi = *(const float2*)&bv[col - 5120];
    s.x += bi.x; s.y += bi.y;
    if (col < 5120) {    // RoPE (pair-interleaved)
        int d2 = (col >> 1) & 63;
        int i = row & 127;
        float c = fc[i * 64 + d2], sn = fs[i * 64 + d2];
        float re = s.x, im = s.y;
        s.x = re * c - im * sn;
        s.y = re * sn + im * c;
    }
    __align__(4) half_t hh[2] = {(half_t)s.x, (half_t)s.y};
    if (col < 4096) {
        *(unsigned int*)&q16[(size_t)row * 4096 + col] = *(unsigned int*)hh;
    } else if (col < 5120) {
        *(unsigned int*)&k16[(size_t)row * 1024 + (col - 4096)] = *(unsigned int*)hh;
    } else {
        int c = col - 5120;
        int kv = c >> 7, d = c & 127;
        int b = row >> 7, i = row & 127;
        size_t base = ((size_t)(b * 8 + kv) * 128 + d) * 128 + i;
        vt16[base]       = hh[0];
        vt16[base + 128] = hh[1];
    }
}

// ---------------------------------------------------------------------------
// Fused attention: one block per (b, h, 32-row q-chunk). Grid 512.
__global__ __launch_bounds__(256, 2)
void fused_attn(const half_t* __restrict__ q16, const half_t* __restrict__ k16,
                const half_t* __restrict__ vt16, half_t* __restrict__ a16) {
    __shared__ __align__(16) char lds[62464];
    half_t (*Qs)[136] = (half_t(*)[136])lds;            //  8704 B
    half_t (*Ks)[136] = (half_t(*)[136])(lds + 8704);   // 34816 B
    float (*Ps)[132]  = (float(*)[132])(lds + 43520);   // 16896 B
    float (*red)[16]  = (float(*)[16])(lds + 60416);    //  2048 B

    const int tid = threadIdx.x;
    const int qi = blockIdx.x & 3, h = (blockIdx.x >> 2) & 31, b = blockIdx.x >> 7;
    const int kv = h >> 2;
    const int qbase = qi * 32;
    const int lane = tid & 63, w = tid >> 6;
    const int quad = lane >> 4, l16 = lane & 15;
    const int m0 = (w & 1) * 16, half64 = (w >> 1) * 64;

#pragma unroll
    for (int p = 0; p < 2; ++p) {
        int task = tid + p * 256;
        int r = task >> 4, c = task & 15;
        *(uint4*)&Qs[r][c * 8] =
            *(const uint4*)&q16[((size_t)(b * 128 + qbase + r) * 32 + h) * 128 + c * 8];
    }
#pragma unroll
    for (int p = 0; p < 8; ++p) {
        int task = tid + p * 256;
        int r = task >> 4, c = task & 15;
        *(uint4*)&Ks[r][c * 8] =
            *(const uint4*)&k16[((size_t)(b * 128 + r) * 8 + kv) * 128 + c * 8];
    }
    __syncthreads();

    // phase 1: S = Q K^T
    f32x4 s[4] = {};
#pragma unroll
    for (int kc = 0; kc < 4; ++kc) {
        f16x8 af = *(const f16x8*)&Qs[m0 + l16][kc * 32 + quad * 8];
#pragma unroll
        for (int jb = 0; jb < 4; ++jb) {
            f16x8 bf = *(const f16x8*)&Ks[half64 + jb * 16 + l16][kc * 32 + quad * 8];
            s[jb] = __builtin_amdgcn_mfma_f32_16x16x32_f16(af, bf, s[jb], 0, 0, 0);
        }
    }
#pragma unroll
    for (int jb = 0; jb < 4; ++jb) {
        int j = half64 + jb * 16 + l16;
#pragma unroll
        for (int rg = 0; rg < 4; ++rg) {
            int row = m0 + quad * 4 + rg;
            Ps[row][j] = (j <= qbase + row) ? s[jb][rg] * SCALE_ : -1e30f;
        }
    }
    __syncthreads();

    // softmax: thread t -> row r, 16-col segment seg
    const int r = tid >> 3, seg = tid & 7;
    float mx = -1e30f;
#pragma unroll
    for (int i = 0; i < 16; ++i) mx = fmaxf(mx, Ps[r][seg * 16 + i]);
    red[r][seg] = mx;
    __syncthreads();

    uint4 vstage[8];
#pragma unroll
    for (int p = 0; p < 8; ++p) {
        int task = tid + p * 256;
        int rr = task >> 4, c = task & 15;
        vstage[p] = *(const uint4*)&vt16[((size_t)(b * 8 + kv) * 128 + rr) * 128 + c * 8];
    }
    float m = red[r][0];
#pragma unroll
    for (int i = 1; i < 8; ++i) m = fmaxf(m, red[r][i]);
    float sum = 0.f;
#pragma unroll
    for (int i = 0; i < 16; ++i) {
        float e = __expf(Ps[r][seg * 16 + i] - m);
        Ps[r][seg * 16 + i] = e;
        sum += e;
    }
    red[r][8 + seg] = sum;
#pragma unroll
    for (int p = 0; p < 8; ++p) {
        int task = tid + p * 256;
        int rr = task >> 4, c = task & 15;
        *(uint4*)&Ks[rr][c * 8] = vstage[p];   // Vt[d][j]
    }
    __syncthreads();

    float tot = 0.f;
#pragma unroll
    for (int i = 0; i < 8; ++i) tot += red[r][8 + i];
    float inv = 1.0f / tot;
#pragma unroll
    for (int i = 0; i < 16; ++i)
        Qs[r][seg * 16 + i] = (half_t)(Ps[r][seg * 16 + i] * inv);
    __syncthreads();

    // phase 2: O = P V
    f32x4 o[4] = {};
#pragma unroll
    for (int jc = 0; jc < 4; ++jc) {
        f16x8 af = *(const f16x8*)&Qs[m0 + l16][jc * 32 + quad * 8];
#pragma unroll
        for (int db = 0; db < 4; ++db) {
            f16x8 bf = *(const f16x8*)&Ks[half64 + db * 16 + l16][jc * 32 + quad * 8];
            o[db] = __builtin_amdgcn_mfma_f32_16x16x32_f16(af, bf, o[db], 0, 0, 0);
        }
    }
#pragma unroll
    for (int db = 0; db < 4; ++db) {
        int d = half64 + db * 16 + l16;
#pragma unroll
        for (int rg = 0; rg < 4; ++rg) {
            int row = m0 + quad * 4 + rg;
            a16[(size_t)(b * 128 + qbase + row) * 4096 + h * 128 + d] = (half_t)o[db][rg];
        }
    }
}

// ---------------------------------------------------------------------------
// O projection gemm, split-K, 128x128 tiles. Grid 128*z.
__global__ __launch_bounds__(256, 3)
void gemm_o(const half_t* __restrict__ a16, const half_t* __restrict__ WtO,
            float* __restrict__ Part, int kslice) {
    __shared__ __align__(16) char lds[49152];
    const int bx = blockIdx.x;
    const int nb = bx % 32, mb = (bx / 32) & 3, zi = bx / 128;
    const int m0 = mb * 128, n0 = nb * 128;
    f32x4 acc[4][4] = {};
    gemm128_bk32(a16, WtO, 4096, m0, n0, zi * kslice, kslice / 32, lds, acc);
    const int tid = threadIdx.x;
    const int lane = tid & 63;
    const int quad = lane >> 4, l16 = lane & 15;
    const int w = tid >> 6;
    const int wm = (w & 1) * 64, wn = (w >> 1) * 64;
    float* Cp = Part + (size_t)zi * ((size_t)M_ * 4096);
#pragma unroll
    for (int i = 0; i < 4; ++i)
#pragma unroll
        for (int j = 0; j < 4; ++j) {
            int col = n0 + wn + j * 16 + l16;
            int rowb = m0 + wm + i * 16 + quad * 4;
#pragma unroll
            for (int rg = 0; rg < 4; ++rg)
                Cp[(size_t)(rowb + rg) * 4096 + col] = acc[i][j][rg];
        }
}

// ---------------------------------------------------------------------------
// out = sum_z PartO[z] + bo.  One thread per float4. Grid 2048.
__global__ void o_reduce(const float* __restrict__ Part, int nz,
                         const float* __restrict__ bo, float* __restrict__ out) {
    const size_t off = (size_t)(blockIdx.x * 256 + threadIdx.x) * 4;
    float4 s = *(const float4*)&Part[off];
    for (int z = 1; z < nz; ++z) {
        float4 p = *(const float4*)&Part[(size_t)z * ((size_t)M_ * 4096) + off];
        s.x += p.x; s.y += p.y; s.z += p.z; s.w += p.w;
    }
    float4 b = *(const float4*)&bo[off & 4095];
    s.x += b.x; s.y += b.y; s.z += b.z; s.w += b.w;
    *(float4*)&out[off] = s;
}

// ---------------------------------------------------------------------------
extern "C" void kernel_launch(void* const* d_in, const int* in_sizes, int n_in,
                              void* d_out, int out_size, void* d_ws, size_t ws_size,
                              hipStream_t stream) {
    const float* x    = (const float*)d_in[0];
    const float* fc   = (const float*)d_in[2];
    const float* fs   = (const float*)d_in[3];
    const float* wq   = (const float*)d_in[7];
    const float* bq   = (const float*)d_in[8];
    const float* wk   = (const float*)d_in[9];
    const float* bk   = (const float*)d_in[10];
    const float* wv   = (const float*)d_in[11];
    const float* bv   = (const float*)d_in[12];
    const float* wo   = (const float*)d_in[13];
    const float* bo   = (const float*)d_in[14];
    float* out = (float*)d_out;

    half_t* x16  = (half_t*)d_ws;            //  2,097,152 h
    half_t* a16  = x16 + 2097152;            //  2,097,152 h
    half_t* q16  = a16 + 2097152;            //  2,097,152 h
    half_t* k16  = q16 + 2097152;            //    524,288 h
    half_t* vt16 = k16 + 524288;             //    524,288 h
    half_t* Wt   = vt16 + 524288;            // 25,165,824 h (ends @65,011,712 B)
    half_t* WtO  = Wt + 25165824;            // 16,777,216 h (32 MB)
    const size_t fixedA = 65011712 + (size_t)16777216 * 2;   // 98,566,144 B
    float* Part = (float*)((char*)d_ws + fixedA);

    int z = (ws_size >= fixedA + 4 * (size_t)12582912) ? 4 : 2;
    const int kslice = 4096 / z;

    // 1. QKV weight transpose (2-tile pipelined blocks) + x convert
    prep_qkv<<<2048, 256, 0, stream>>>(wq, wk, wv, x, Wt, x16);

    // 2. QKV gemm (split-K, conflict-free BK=32 pipeline) + packed wo-T
    gemm_qkv_pack<<<192 * z + 2048, 256, 0, stream>>>(x16, Wt, Part, kslice,
                                                      192 * z, wo, WtO);

    // 3. reduce + bias + rope -> fp16 q/k/vt
    qkv_reduce_rope<<<dim3(12, 512), 256, 0, stream>>>(Part, z, bq, bk, bv,
                                                       fc, fs, q16, k16, vt16);

    // 4. fused attention
    fused_attn<<<512, 256, 0, stream>>>(q16, k16, vt16, a16);

    // 5. O projection (split-K) + reduce
    gemm_o<<<128 * z, 256, 0, stream>>>(a16, WtO, Part, kslice);
    o_reduce<<<2048, 256, 0, stream>>>(Part, z, bo, out);
}

// Round 9
// 282.002 us; speedup vs baseline: 1.1013x; 1.1013x over previous
//
#include <hip/hip_runtime.h>
#include <math.h>

// GroupedQueryAttention: B=4,S=128,D=4096,H=32,KV=8,HD=128,REP=4
// Round 13 (2nd resubmit; r7/r8 benches were GPU-acquisition timeouts,
// kernel never ran): r3 (283us, best measured) with exactly two edits:
//  1. wo-transpose blocks moved from the attention launch into the QKV-gemm
//     launch (r0-proven: hidden under gemm's idle BW; gemm runs at 1 TB/s).
//     Attention is now a pure 512-block launch (~13us).
//  2. s_setprio(1) around the QKV gemm MFMA cluster - transpose waves now
//     co-reside on each CU, giving the CU scheduler role diversity (T5's
//     measured precondition). Not applied to gemm_o (lockstep, null).
// Everything else identical to r3: prep (47.6us known), full-K gemms with
// 3-buffer depth-2 counted vmcnt(6) pipeline, fused bias+RoPE epilogue,
// no HBM partials, 4 launches total.

#define B_   4
#define S_   128
#define D_   4096
#define H_   32
#define KV_  8
#define HD_  128
#define M_   (B_ * S_)        // 512 rows
#define NQKV 6144
#define SCALE_ 0.088388347648318447f  // 1/sqrt(128)

typedef _Float16 half_t;
typedef half_t f16x8 __attribute__((ext_vector_type(8)));
typedef float  f32x4 __attribute__((ext_vector_type(4)));

__device__ inline void load_lds16(const void* g, void* l) {
    __builtin_amdgcn_global_load_lds((const __attribute__((address_space(1))) void*)g,
                                     (__attribute__((address_space(3))) void*)l,
                                     16, 0, 0);
}

// ---------------------------------------------------------------------------
// One 128n x 64k transpose tile: W[k0..+64][nsrc0..+128] fp32 ->
// Wt slab (k0/64): rows ndst0..+128 x 64 halfs (16KB contiguous region).
// 256 threads. (r3-measured structure.)
__device__ void transpose_tile(const float* __restrict__ src, int Nsrc, int nsrc0,
                               int ndst0, int k0, int Ntot,
                               half_t* __restrict__ Wt, void* ldsraw) {
    float (*tile)[132] = (float(*)[132])ldsraw;   // [64k][128n], pad 132
    const int t = threadIdx.x;
#pragma unroll
    for (int p = 0; p < 8; ++p) {
        int idx = t + p * 256;              // 2048 float4 tasks
        int r = idx >> 5, c4 = idx & 31;    // 64 k-rows x 32 float4
        *(float4*)&tile[r][c4 * 4] =
            *(const float4*)&src[(size_t)(k0 + r) * Nsrc + nsrc0 + c4 * 4];
    }
    __syncthreads();
    const int n = t >> 1, kh = t & 1;       // 128 n-rows, 2 k-halves of 32
    __align__(16) half_t hs[32];
#pragma unroll
    for (int i = 0; i < 32; ++i)
        hs[i] = (half_t)tile[kh * 32 + i][n];
    size_t ob = ((size_t)(k0 >> 6) * Ntot + ndst0 + n) * 64 + kh * 32;
#pragma unroll
    for (int u = 0; u < 4; ++u)
        *(uint4*)&Wt[ob + u * 8] = *(uint4*)&hs[u * 8];
}

// ---------------------------------------------------------------------------
// Packed: QKV weight transpose (3072 blocks) + x fp32->fp16 (512 blocks).
__global__ __launch_bounds__(256)
void prep_qkv(const float* __restrict__ wq, const float* __restrict__ wk,
              const float* __restrict__ wv, const float* __restrict__ x,
              half_t* __restrict__ Wt, half_t* __restrict__ x16) {
    __shared__ __align__(16) char lds[33792];
    const int bx = blockIdx.x;
    if (bx < 3072) {
        int nt = bx % 48, kt = bx / 48;
        const float* src; int Nsrc, ns0, nd0;
        if (nt < 32)      { src = wq; Nsrc = 4096; ns0 = nt * 128;        nd0 = nt * 128; }
        else if (nt < 40) { src = wk; Nsrc = 1024; ns0 = (nt - 32) * 128; nd0 = 4096 + (nt - 32) * 128; }
        else              { src = wv; Nsrc = 1024; ns0 = (nt - 40) * 128; nd0 = 5120 + (nt - 40) * 128; }
        transpose_tile(src, Nsrc, ns0, nd0, kt * 64, NQKV, Wt, lds);
    } else {
        int i0 = (bx - 3072) * 1024 + threadIdx.x;
#pragma unroll
        for (int j = 0; j < 4; ++j) {
            int i = i0 + j * 256;
            float4 f = ((const float4*)x)[i];
            __align__(8) half_t h4[4] = {(half_t)f.x, (half_t)f.y, (half_t)f.z, (half_t)f.w};
            ((uint2*)x16)[i] = *(uint2*)h4;
        }
    }
}

// ---------------------------------------------------------------------------
// 64m x 128n full-K=4096 gemm core, 256 threads (4 waves, each 64m x 32n).
// 3 LDS buffers, depth-2 DMA prefetch, counted vmcnt(6) + raw s_barrier:
// tile t+2's 6 loads/wave stay in flight across the barrier ending step t.
__device__ __forceinline__ void stage64x128(const half_t* __restrict__ A,
                                            const half_t* __restrict__ Bbase,
                                            int N, int m0, int n0, int kc,
                                            half_t* AsD, half_t* BsD, int tid) {
    const int lane = tid & 63, tB = tid & 192;
    const half_t* Bslab = Bbase + ((size_t)(kc >> 6) * N + n0) * 64;
#pragma unroll
    for (int p = 0; p < 2; ++p) {           // A: 512 tasks (64 rows x 8 chunks)
        int tb = p * 256 + tB;
        int task = tb + lane;
        int r = task >> 3, os = (task ^ r) & 7;
        load_lds16(&A[(size_t)(m0 + r) * 4096 + kc + os * 8], AsD + tb * 8);
    }
#pragma unroll
    for (int p = 0; p < 4; ++p) {           // B: 1024 tasks (128 rows x 8 chunks)
        int tb = p * 256 + tB;
        int task = tb + lane;
        int r = task >> 3, os = (task ^ r) & 7;
        load_lds16(&Bslab[(size_t)r * 64 + os * 8], BsD + tb * 8);
    }
}

template <bool PRIO>
__device__ __forceinline__ void compute64x128(const half_t* AsD, const half_t* BsD,
                                              int tid, f32x4 (&acc)[4][2]) {
    const int lane = tid & 63;
    const int quad = lane >> 4, l16 = lane & 15;
    const int wn = (tid >> 6) * 32;
    half_t (*As)[64] = (half_t(*)[64])AsD;
    half_t (*Bs)[64] = (half_t(*)[64])BsD;
#pragma unroll
    for (int kk = 0; kk < 2; ++kk) {
        f16x8 af[4], bf[2];
        int L = kk * 4 + quad;
#pragma unroll
        for (int i = 0; i < 4; ++i) {
            int ra = i * 16 + l16;
            af[i] = *(const f16x8*)&As[ra][(L ^ (ra & 7)) * 8];
        }
#pragma unroll
        for (int j = 0; j < 2; ++j) {
            int rb = wn + j * 16 + l16;
            bf[j] = *(const f16x8*)&Bs[rb][(L ^ (rb & 7)) * 8];
        }
        if (PRIO) __builtin_amdgcn_s_setprio(1);
#pragma unroll
        for (int i = 0; i < 4; ++i)
#pragma unroll
            for (int j = 0; j < 2; ++j)
                acc[i][j] = __builtin_amdgcn_mfma_f32_16x16x32_f16(af[i], bf[j], acc[i][j], 0, 0, 0);
        if (PRIO) __builtin_amdgcn_s_setprio(0);
    }
}

__device__ __forceinline__ void fence_step(int n) {
    // wait until only n VMEM ops outstanding, then barrier WITHOUT draining
    if (n == 6)      asm volatile("s_waitcnt vmcnt(6)" ::: "memory");
    else if (n == 0) asm volatile("s_waitcnt vmcnt(0)" ::: "memory");
    __builtin_amdgcn_s_barrier();
    __builtin_amdgcn_sched_barrier(0);
}

template <bool PRIO>
__device__ __forceinline__ void gemm64x128(const half_t* __restrict__ A,
                                           const half_t* __restrict__ Bbase,
                                           int N, int m0, int n0, char* lds,
                                           f32x4 (&acc)[4][2]) {
    const int tid = threadIdx.x;
    half_t* As0 = (half_t*)lds;              // [3][64][64]   24KB
    half_t* Bs0 = (half_t*)(lds + 24576);    // [3][128][64]  48KB
    // prologue: tiles 0 and 1 in flight (12 loads/wave)
    stage64x128(A, Bbase, N, m0, n0, 0,  As0,        Bs0,        tid);
    stage64x128(A, Bbase, N, m0, n0, 64, As0 + 4096, Bs0 + 8192, tid);
    fence_step(6);                           // tile 0 landed; tile 1 in flight
    int cur = 0, pf = 2;
    for (int it = 0; it < 62; ++it) {
        stage64x128(A, Bbase, N, m0, n0, (it + 2) * 64,
                    As0 + pf * 4096, Bs0 + pf * 8192, tid);
        compute64x128<PRIO>(As0 + cur * 4096, Bs0 + cur * 8192, tid, acc);
        fence_step(6);                       // tile it+1 landed; it+2 in flight
        cur = (cur == 2) ? 0 : cur + 1;
        pf  = (pf  == 2) ? 0 : pf  + 1;
    }
    compute64x128<PRIO>(As0 + cur * 4096, Bs0 + cur * 8192, tid, acc);  // 62
    fence_step(0);                           // tile 63 landed
    cur = (cur == 2) ? 0 : cur + 1;
    compute64x128<PRIO>(As0 + cur * 4096, Bs0 + cur * 8192, tid, acc);  // 63
    __syncthreads();                         // LDS free for epilogue reuse
}

// ---------------------------------------------------------------------------
// Packed: QKV gemm (384 blocks, full-K, fused bias+RoPE+fp16 epilogue)
// + wo transpose (2048 blocks, hidden under the gemm's idle BW).
__global__ __launch_bounds__(256, 2)
void gemm_qkv_pack(const half_t* __restrict__ x16, const half_t* __restrict__ Wt,
                   const float* __restrict__ bq, const float* __restrict__ bk,
                   const float* __restrict__ bv, const float* __restrict__ fc,
                   const float* __restrict__ fs, half_t* __restrict__ q16,
                   half_t* __restrict__ k16, half_t* __restrict__ vt16,
                   const float* __restrict__ wo, half_t* __restrict__ WtO) {
    __shared__ __align__(16) char lds[73728];
    const int bx = blockIdx.x;
    if (bx >= 384) {
        int t = bx - 384;                    // 2048 = 32 n-tiles x 64 k-tiles
        transpose_tile(wo, 4096, (t & 31) * 128, (t & 31) * 128, (t >> 5) * 64,
                       4096, WtO, lds);
        return;
    }
    const int o = (bx & 7) * 48 + (bx >> 3);  // bijective, 384 = 8 XCD x 48
    const int nb = o >> 3, mb = o & 7;
    const int m0 = mb * 64, n0 = nb * 128;

    f32x4 acc[4][2] = {};
    gemm64x128<true>(x16, Wt, NQKV, m0, n0, lds, acc);

    const int tid = threadIdx.x;
    const int lane = tid & 63;
    const int quad = lane >> 4, l16 = lane & 15;
    const int wn = (tid >> 6) * 32;

    if (n0 < 5120) {
        // Q or K tile: bias + RoPE (adjacent-lane pairs) + fp16 store
        const bool isQ = n0 < 4096;
        const float* bias = isQ ? bq : bk;
        const int bOff = isQ ? 0 : 4096;
        half_t* dst = isQ ? q16 : k16;
        const int ldd = isQ ? 4096 : 1024;
#pragma unroll
        for (int i = 0; i < 4; ++i)
#pragma unroll
            for (int j = 0; j < 2; ++j) {
                const int col = n0 + wn + j * 16 + l16;   // even iff l16 even
                const int d2 = (col >> 1) & 63;
                const float bcol = bias[col - bOff];
#pragma unroll
                for (int rg = 0; rg < 4; ++rg) {
                    const int row = m0 + i * 16 + quad * 4 + rg;
                    float v = acc[i][j][rg] + bcol;
                    float p = __shfl_xor(v, 1);           // (re,im) partner
                    const int iloc = row & 127;
                    const float c = fc[iloc * 64 + d2], sn = fs[iloc * 64 + d2];
                    float ov = (l16 & 1) ? (p * sn + v * c)   // im' = re*s + im*c
                                         : (v * c - p * sn);  // re' = re*c - im*s
                    float o2 = __shfl_xor(ov, 1);
                    if (!(l16 & 1)) {
                        __align__(4) half_t hh[2] = {(half_t)ov, (half_t)o2};
                        *(unsigned int*)&dst[(size_t)row * ldd + (col - bOff)] =
                            *(unsigned int*)hh;
                    }
                }
            }
    } else {
        // V tile: bias -> LDS fp16 -> transposed coalesced store to vt16[d][i]
        half_t (*Th)[136] = (half_t(*)[136])lds;   // 64 x 136 x 2 = 17408 B
#pragma unroll
        for (int i = 0; i < 4; ++i)
#pragma unroll
            for (int j = 0; j < 2; ++j) {
                const int cl = wn + j * 16 + l16;
                const float bcol = bv[n0 - 5120 + cl];
#pragma unroll
                for (int rg = 0; rg < 4; ++rg)
                    Th[i * 16 + quad * 4 + rg][cl] = (half_t)(acc[i][j][rg] + bcol);
            }
        __syncthreads();
        const int d = tid >> 1, ih = tid & 1;     // 128 d x 2 i-halves of 32
        const int kv = (n0 - 5120) >> 7;
        const int b = mb >> 1, i0 = (mb & 1) * 64;
        __align__(16) half_t hs[32];
#pragma unroll
        for (int u = 0; u < 32; ++u) hs[u] = Th[ih * 32 + u][d];
        size_t base = ((size_t)(b * 8 + kv) * 128 + d) * 128 + i0 + ih * 32;
#pragma unroll
        for (int u = 0; u < 4; ++u)
            *(uint4*)&vt16[base + u * 8] = *(uint4*)&hs[u * 8];
    }
}

// ---------------------------------------------------------------------------
// Fused attention: one block per (b, h, 32-row q-chunk). Grid 512.
__global__ __launch_bounds__(256, 2)
void fused_attn(const half_t* __restrict__ q16, const half_t* __restrict__ k16,
                const half_t* __restrict__ vt16, half_t* __restrict__ a16) {
    __shared__ __align__(16) char lds[62464];
    half_t (*Qs)[136] = (half_t(*)[136])lds;            //  8704 B
    half_t (*Ks)[136] = (half_t(*)[136])(lds + 8704);   // 34816 B
    float (*Ps)[132]  = (float(*)[132])(lds + 43520);   // 16896 B
    float (*red)[16]  = (float(*)[16])(lds + 60416);    //  2048 B

    const int tid = threadIdx.x;
    const int qi = blockIdx.x & 3, h = (blockIdx.x >> 2) & 31, b = blockIdx.x >> 7;
    const int kv = h >> 2;
    const int qbase = qi * 32;
    const int lane = tid & 63, w = tid >> 6;
    const int quad = lane >> 4, l16 = lane & 15;
    const int m0 = (w & 1) * 16, half64 = (w >> 1) * 64;

#pragma unroll
    for (int p = 0; p < 2; ++p) {
        int task = tid + p * 256;
        int r = task >> 4, c = task & 15;
        *(uint4*)&Qs[r][c * 8] =
            *(const uint4*)&q16[((size_t)(b * 128 + qbase + r) * 32 + h) * 128 + c * 8];
    }
#pragma unroll
    for (int p = 0; p < 8; ++p) {
        int task = tid + p * 256;
        int r = task >> 4, c = task & 15;
        *(uint4*)&Ks[r][c * 8] =
            *(const uint4*)&k16[((size_t)(b * 128 + r) * 8 + kv) * 128 + c * 8];
    }
    __syncthreads();

    // phase 1: S = Q K^T
    f32x4 s[4] = {};
#pragma unroll
    for (int kc = 0; kc < 4; ++kc) {
        f16x8 af = *(const f16x8*)&Qs[m0 + l16][kc * 32 + quad * 8];
#pragma unroll
        for (int jb = 0; jb < 4; ++jb) {
            f16x8 bf = *(const f16x8*)&Ks[half64 + jb * 16 + l16][kc * 32 + quad * 8];
            s[jb] = __builtin_amdgcn_mfma_f32_16x16x32_f16(af, bf, s[jb], 0, 0, 0);
        }
    }
#pragma unroll
    for (int jb = 0; jb < 4; ++jb) {
        int j = half64 + jb * 16 + l16;
#pragma unroll
        for (int rg = 0; rg < 4; ++rg) {
            int row = m0 + quad * 4 + rg;
            Ps[row][j] = (j <= qbase + row) ? s[jb][rg] * SCALE_ : -1e30f;
        }
    }
    __syncthreads();

    // softmax: thread t -> row r, 16-col segment seg
    const int r = tid >> 3, seg = tid & 7;
    float mx = -1e30f;
#pragma unroll
    for (int i = 0; i < 16; ++i) mx = fmaxf(mx, Ps[r][seg * 16 + i]);
    red[r][seg] = mx;
    __syncthreads();

    uint4 vstage[8];
#pragma unroll
    for (int p = 0; p < 8; ++p) {
        int task = tid + p * 256;
        int rr = task >> 4, c = task & 15;
        vstage[p] = *(const uint4*)&vt16[((size_t)(b * 8 + kv) * 128 + rr) * 128 + c * 8];
    }
    float m = red[r][0];
#pragma unroll
    for (int i = 1; i < 8; ++i) m = fmaxf(m, red[r][i]);
    float sum = 0.f;
#pragma unroll
    for (int i = 0; i < 16; ++i) {
        float e = __expf(Ps[r][seg * 16 + i] - m);
        Ps[r][seg * 16 + i] = e;
        sum += e;
    }
    red[r][8 + seg] = sum;
#pragma unroll
    for (int p = 0; p < 8; ++p) {
        int task = tid + p * 256;
        int rr = task >> 4, c = task & 15;
        *(uint4*)&Ks[rr][c * 8] = vstage[p];   // Vt[d][j]
    }
    __syncthreads();

    float tot = 0.f;
#pragma unroll
    for (int i = 0; i < 8; ++i) tot += red[r][8 + i];
    float inv = 1.0f / tot;
#pragma unroll
    for (int i = 0; i < 16; ++i)
        Qs[r][seg * 16 + i] = (half_t)(Ps[r][seg * 16 + i] * inv);
    __syncthreads();

    // phase 2: O = P V
    f32x4 o[4] = {};
#pragma unroll
    for (int jc = 0; jc < 4; ++jc) {
        f16x8 af = *(const f16x8*)&Qs[m0 + l16][jc * 32 + quad * 8];
#pragma unroll
        for (int db = 0; db < 4; ++db) {
            f16x8 bf = *(const f16x8*)&Ks[half64 + db * 16 + l16][jc * 32 + quad * 8];
            o[db] = __builtin_amdgcn_mfma_f32_16x16x32_f16(af, bf, o[db], 0, 0, 0);
        }
    }
#pragma unroll
    for (int db = 0; db < 4; ++db) {
        int d = half64 + db * 16 + l16;
#pragma unroll
        for (int rg = 0; rg < 4; ++rg) {
            int row = m0 + quad * 4 + rg;
            a16[(size_t)(b * 128 + qbase + row) * 4096 + h * 128 + d] = (half_t)o[db][rg];
        }
    }
}

// ---------------------------------------------------------------------------
// O projection + fused +bo, fp32 store. Grid 256 = 8 m x 32 n, XCD-swizzled.
__global__ __launch_bounds__(256, 2)
void gemm_o_fused(const half_t* __restrict__ a16, const half_t* __restrict__ WtO,
                  const float* __restrict__ bo, float* __restrict__ out) {
    __shared__ __align__(16) char lds[73728];
    const int bx = blockIdx.x;
    const int o = (bx & 7) * 32 + (bx >> 3);  // bijective, 256 = 8 XCD x 32
    const int nb = o >> 3, mb = o & 7;
    const int m0 = mb * 64, n0 = nb * 128;

    f32x4 acc[4][2] = {};
    gemm64x128<false>(a16, WtO, 4096, m0, n0, lds, acc);

    const int tid = threadIdx.x;
    const int lane = tid & 63;
    const int quad = lane >> 4, l16 = lane & 15;
    const int wn = (tid >> 6) * 32;
#pragma unroll
    for (int i = 0; i < 4; ++i)
#pragma unroll
        for (int j = 0; j < 2; ++j) {
            const int col = n0 + wn + j * 16 + l16;
            const float bcol = bo[col];
#pragma unroll
            for (int rg = 0; rg < 4; ++rg) {
                const int row = m0 + i * 16 + quad * 4 + rg;
                out[(size_t)row * 4096 + col] = acc[i][j][rg] + bcol;
            }
        }
}

// ---------------------------------------------------------------------------
extern "C" void kernel_launch(void* const* d_in, const int* in_sizes, int n_in,
                              void* d_out, int out_size, void* d_ws, size_t ws_size,
                              hipStream_t stream) {
    const float* x    = (const float*)d_in[0];
    const float* fc   = (const float*)d_in[2];
    const float* fs   = (const float*)d_in[3];
    const float* wq   = (const float*)d_in[7];
    const float* bq   = (const float*)d_in[8];
    const float* wk   = (const float*)d_in[9];
    const float* bk   = (const float*)d_in[10];
    const float* wv   = (const float*)d_in[11];
    const float* bv   = (const float*)d_in[12];
    const float* wo   = (const float*)d_in[13];
    const float* bo   = (const float*)d_in[14];
    float* out = (float*)d_out;

    half_t* x16  = (half_t*)d_ws;            //  2,097,152 h
    half_t* a16  = x16 + 2097152;            //  2,097,152 h
    half_t* q16  = a16 + 2097152;            //  2,097,152 h
    half_t* k16  = q16 + 2097152;            //    524,288 h
    half_t* vt16 = k16 + 524288;             //    524,288 h
    half_t* Wt   = vt16 + 524288;            // 25,165,824 h (ends @65,011,712 B)
    half_t* WtO  = Wt + 25165824;            // 16,777,216 h (32 MB) - separate:
                                             // written while Wt is being read.

    // 1. QKV weight transpose + x convert
    prep_qkv<<<3584, 256, 0, stream>>>(wq, wk, wv, x, Wt, x16);

    // 2. QKV gemm (full-K, depth-2 counted-vmcnt, fused RoPE epilogue)
    //    + wo transpose packed into the same launch's idle BW
    gemm_qkv_pack<<<384 + 2048, 256, 0, stream>>>(x16, Wt, bq, bk, bv, fc, fs,
                                                  q16, k16, vt16, wo, WtO);

    // 3. fused attention (pure, 512 blocks)
    fused_attn<<<512, 256, 0, stream>>>(q16, k16, vt16, a16);

    // 4. O projection, full-K, fused +bo
    gemm_o_fused<<<256, 256, 0, stream>>>(a16, WtO, bo, out);
}